// Round 2
// baseline (266.392 us; speedup 1.0000x reference)
//
#include <hip/hip_runtime.h>

// 3-layer GraphConv (PyG) + softmax, 100k nodes, 1.6M edges, f32 in/out.
// R2: f32 global atomics ~306G/s scattered -> pull-gather wins.
// R5: two-phase placement fixed build; transform store-amp found (94us).
// R7: linear2 (scalar-path weights, register accs) fixed transform.
// R9: fully deterministic build (zero global atomics). gather32 = 44.5us.
// R10: staged gather unroll: no change (248us) -> gathers are L3-gather-
//      BYTES bound (gather32 = 205MB from L3 = 4.6 TB/s).
// R11: fp16 t-tables FAILED accuracy: 5.08e-2 > 2e-2 (quant noise rel
//      ~4.9e-4 amplified equally with signal through 3 agg layers; absmax
//      samples the 100k-node tail).
// R12: row-scaled int16 t-tables (q = v*32767/rowmax, f32 scale per row).
//      ~12x lower quant noise than fp16 at same 2 B/elem gather traffic.
//      Predicted absmax ~5e-3. Quantization fused into linear (row already
//      in registers). Flat workspace layout (46/268 MB), no aliasing.

#define RNODES 128
#define NB_MAX 1024
#define CH 4096            // edges per chunk
#define CMAX 512           // max chunks (scan_chunkhist: one chunk/thread)

// ------- fused linear: t=quant(x@Wrel) int16+scale, acc=x@Wroot+b (f32) ----
template <int Fin, int Fout, bool RELU>
__global__ void linear_fused_q_kernel(const float* __restrict__ x,
                                      const float* __restrict__ Wrel,
                                      const float* __restrict__ Wroot,
                                      const float* __restrict__ bias,
                                      short* __restrict__ t,
                                      float* __restrict__ tscale,
                                      float* __restrict__ acc, int N) {
    int n = blockIdx.x * blockDim.x + threadIdx.x;
    if (n >= N) return;

    float orel[Fout], oroot[Fout];
#pragma unroll
    for (int f = 0; f < Fout; ++f) { orel[f] = 0.f; oroot[f] = 0.f; }

    const float* xr = x + (size_t)n * Fin;
#pragma unroll
    for (int k = 0; k < Fin; k += 4) {
        float4 v = *(const float4*)(xr + k);
        if (RELU) {
            v.x = fmaxf(v.x, 0.f); v.y = fmaxf(v.y, 0.f);
            v.z = fmaxf(v.z, 0.f); v.w = fmaxf(v.w, 0.f);
        }
        const float xv[4] = {v.x, v.y, v.z, v.w};
#pragma unroll
        for (int kk = 0; kk < 4; ++kk) {
            const float* wr1 = Wrel  + (size_t)(k + kk) * Fout;
            const float* wr2 = Wroot + (size_t)(k + kk) * Fout;
#pragma unroll
            for (int f = 0; f < Fout; ++f) {
                orel[f]  = fmaf(xv[kk], wr1[f], orel[f]);
                oroot[f] = fmaf(xv[kk], wr2[f], oroot[f]);
            }
        }
    }

    // --- row-scaled int16 quantization of the rel output (gathered table) ---
    float m = 0.f;
#pragma unroll
    for (int f = 0; f < Fout; ++f) m = fmaxf(m, fabsf(orel[f]));
    const float inv = (m > 0.f) ? (32767.0f / m) : 0.f;
    tscale[n] = m * (1.0f / 32767.0f);

    short q[Fout];
#pragma unroll
    for (int f = 0; f < Fout; ++f) q[f] = (short)__float2int_rn(orel[f] * inv);

    short* trow = t + (size_t)n * Fout;
    if constexpr (Fout >= 8) {
#pragma unroll
        for (int f = 0; f < Fout; f += 8)
            *(int4*)(trow + f) = *(const int4*)(q + f);    // 16B stores
    } else {
        *(int*)trow = (int)(unsigned short)q[0] | ((int)q[1] << 16);
    }

    // --- root + bias -> acc (f32) ---
#pragma unroll
    for (int f = 0; f < Fout; ++f) oroot[f] += bias[f];
    float* arow = acc + (size_t)n * Fout;
    if constexpr (Fout >= 4) {
#pragma unroll
        for (int f = 0; f < Fout; f += 4)
            *(float4*)(arow + f) = make_float4(oroot[f], oroot[f+1], oroot[f+2], oroot[f+3]);
    } else {
        *(float2*)arow = make_float2(oroot[0], oroot[1]);
    }
}

// ---------------- legacy f32 linear (fallback path only) -------------------
template <int Fin, int Fout, bool RELU>
__global__ void linear2_kernel(const float* __restrict__ x,
                               const float* __restrict__ Wrel,
                               const float* __restrict__ Wroot,
                               const float* __restrict__ bias,
                               float* __restrict__ t,
                               float* __restrict__ acc, int N) {
    const bool rootTask = (blockIdx.y != 0);
    const float* __restrict__ W = rootTask ? Wroot : Wrel;
    float* __restrict__ outp    = rootTask ? acc : t;

    int n = blockIdx.x * blockDim.x + threadIdx.x;
    if (n >= N) return;

    float o[Fout];
#pragma unroll
    for (int f = 0; f < Fout; ++f) o[f] = 0.f;

    const float* xr = x + (size_t)n * Fin;
#pragma unroll
    for (int k = 0; k < Fin; k += 4) {
        float4 v = *(const float4*)(xr + k);
        if (RELU) {
            v.x = fmaxf(v.x, 0.f); v.y = fmaxf(v.y, 0.f);
            v.z = fmaxf(v.z, 0.f); v.w = fmaxf(v.w, 0.f);
        }
        const float xv[4] = {v.x, v.y, v.z, v.w};
#pragma unroll
        for (int kk = 0; kk < 4; ++kk) {
            const float* wr = W + (size_t)(k + kk) * Fout;
#pragma unroll
            for (int f = 0; f < Fout; ++f)
                o[f] = fmaf(xv[kk], wr[f], o[f]);
        }
    }
    if (rootTask) {
#pragma unroll
        for (int f = 0; f < Fout; ++f) o[f] += bias[f];
    }
    float* op = outp + (size_t)n * Fout;
    if constexpr (Fout >= 4) {
#pragma unroll
        for (int f = 0; f < Fout; f += 4)
            *(float4*)(op + f) = make_float4(o[f], o[f + 1], o[f + 2], o[f + 3]);
    } else {
        *(float2*)op = make_float2(o[0], o[1]);
    }
}

// ---------------- build step 1: per-chunk LDS histogram --------------------
__global__ void hist_chunked_kernel(const int* __restrict__ dst,
                                    int* __restrict__ chunkhist,
                                    int nE, int NB) {
    __shared__ int h[NB_MAX];
    const int c  = blockIdx.x;
    const int e0 = c * CH, e1 = min(e0 + CH, nE);
    for (int b = threadIdx.x; b < NB; b += blockDim.x) h[b] = 0;
    __syncthreads();
    for (int e = e0 + threadIdx.x; e < e1; e += blockDim.x)
        atomicAdd(&h[dst[e] >> 7], 1);
    __syncthreads();
    for (int b = threadIdx.x; b < NB; b += blockDim.x)
        chunkhist[(size_t)c * NB + b] = h[b];          // contiguous row flush
}

// ---------------- build step 2: column scan (per bucket over chunks) -------
__global__ void scan_chunkhist_kernel(int* __restrict__ chunkhist,
                                      int* __restrict__ gtotal,
                                      int C, int NB) {
    __shared__ int s[CMAX];
    const int b = blockIdx.x;
    const int t = threadIdx.x;
    int v = (t < C) ? chunkhist[(size_t)t * NB + b] : 0;
    s[t] = v;
    __syncthreads();
    for (int off = 1; off < CMAX; off <<= 1) {
        int u = (t >= off) ? s[t - off] : 0;
        __syncthreads();
        s[t] += u;
        __syncthreads();
    }
    if (t < C) chunkhist[(size_t)t * NB + b] = s[t] - v;   // exclusive
    if (t == CMAX - 1) gtotal[b] = s[t];                   // inclusive total
}

// ---------------- build step 3: bucket scan (single block) -----------------
__global__ void scan_buckets_kernel(const int* __restrict__ gtotal,
                                    int* __restrict__ bptr, int NB, int nE) {
    __shared__ int s[NB_MAX];
    int t = threadIdx.x;
    int own = (t < NB) ? gtotal[t] : 0;
    s[t] = own;
    __syncthreads();
    for (int off = 1; off < NB_MAX; off <<= 1) {
        int v = (t >= off) ? s[t - off] : 0;
        __syncthreads();
        s[t] += v;
        __syncthreads();
    }
    if (t < NB) bptr[t] = s[t] - own;
    if (t == 0) bptr[NB] = nE;
}

// ---------------- build step 4: deterministic placement --------------------
__global__ void bucketize_det_kernel(const int* __restrict__ src,
                                     const int* __restrict__ dst,
                                     const int* __restrict__ chunkpre,
                                     const int* __restrict__ bptr,
                                     unsigned int* __restrict__ records,
                                     int nE, int NB) {
    __shared__ int lcur[NB_MAX];
    const int c  = blockIdx.x;
    const int e0 = c * CH, e1 = min(e0 + CH, nE);
    for (int b = threadIdx.x; b < NB; b += blockDim.x)
        lcur[b] = bptr[b] + chunkpre[(size_t)c * NB + b];
    __syncthreads();
    for (int e = e0 + threadIdx.x; e < e1; e += blockDim.x) {
        int d = dst[e];
        int b = d >> 7;
        int pos = atomicAdd(&lcur[b], 1);                  // LDS-only atomic
        records[pos] = (unsigned int)src[e] | ((unsigned int)(d & 127) << 17);
    }
}

// ---------------- build step 5: per-bucket hist+scan+rowptr+place ----------
__global__ void place_merge_kernel(const unsigned int* __restrict__ records,
                                   const int* __restrict__ bptr,
                                   int* __restrict__ rowptr,
                                   int* __restrict__ srcs_sorted,
                                   int N, int nE, int NB) {
    __shared__ int hist[RNODES];
    __shared__ int s[RNODES];
    __shared__ int lcur[RNODES];
    const int b    = blockIdx.x;
    const int base = b * RNODES;
    const int nn   = min(RNODES, N - base);
    const int beg  = bptr[b], end = bptr[b + 1];
    const int t    = threadIdx.x;

    if (t < RNODES) hist[t] = 0;
    __syncthreads();
    for (int i = beg + t; i < end; i += blockDim.x)
        atomicAdd(&hist[records[i] >> 17], 1);
    __syncthreads();

    if (t < RNODES) s[t] = hist[t];
    __syncthreads();
    for (int off = 1; off < RNODES; off <<= 1) {
        int v = (t < RNODES && t >= off) ? s[t - off] : 0;
        __syncthreads();
        if (t < RNODES && t >= off) s[t] += v;
        __syncthreads();
    }
    if (t < nn) {
        int ex = beg + s[t] - hist[t];
        rowptr[base + t] = ex;
        lcur[t] = ex;
    }
    if (b == NB - 1 && t == 0) rowptr[N] = nE;
    __syncthreads();

    for (int i = beg + t; i < end; i += blockDim.x) {
        unsigned int rec = records[i];
        int pos = atomicAdd(&lcur[rec >> 17], 1);
        srcs_sorted[pos] = (int)(rec & 0x1FFFFu);
    }
}

// ------- pull aggregation: int16 rows + per-row scale, staged 8/1 ----------
// F>=4: F/2 lanes per node, each lane owns one short2 (2 features).
// F==2: 1 lane per node.
template <int F, bool SOFTMAX>
__global__ void gather_agg_q_kernel(const short* __restrict__ t,
                                    const float* __restrict__ tscale,
                                    const int* __restrict__ rowptr,
                                    const int* __restrict__ srcs,
                                    const float* __restrict__ rootacc,
                                    float* __restrict__ out, int N) {
    constexpr int P = (F >= 4) ? (F / 2) : 1;   // lanes per node
    constexpr int S = F / 2;                    // row stride in short2 (ints)
    int tid = blockIdx.x * blockDim.x + threadIdx.x;
    int n  = (P == 1) ? tid : (tid / P);
    int fp = (P == 1) ? 0   : (tid & (P - 1));
    if (n >= N) return;

    const int* tp = (const int*)t;              // short2 viewed as int
    int beg = rowptr[n], end = rowptr[n + 1];
    float sx = 0.f, sy = 0.f;
    int e = beg;
    // stage: 8 concurrent edge gathers (mean degree ~16 -> two batches)
    for (; e + 8 <= end; e += 8) {
        int s[8];
#pragma unroll
        for (int u = 0; u < 8; ++u) s[u] = srcs[e + u];
        int q[8]; float sc[8];
#pragma unroll
        for (int u = 0; u < 8; ++u) {
            q[u]  = tp[s[u] * S + fp];
            sc[u] = tscale[s[u]];
        }
#pragma unroll
        for (int u = 0; u < 8; ++u) {
            float lo = (float)((short)(q[u] & 0xFFFF));
            float hi = (float)(q[u] >> 16);
            sx = fmaf(sc[u], lo, sx);
            sy = fmaf(sc[u], hi, sy);
        }
    }
    // tail (<=7)
    for (; e < end; ++e) {
        int s0 = srcs[e];
        int qv = tp[s0 * S + fp];
        float sc = tscale[s0];
        sx = fmaf(sc, (float)((short)(qv & 0xFFFF)), sx);
        sy = fmaf(sc, (float)(qv >> 16), sy);
    }

    const float2 r0 = *(const float2*)(rootacc + (size_t)n * F + 2 * fp);
    float a = r0.x + sx, b = r0.y + sy;
    if (!SOFTMAX) {
        *(float2*)(out + (size_t)n * F + 2 * fp) = make_float2(a, b);
    } else {
        float m = fmaxf(a, b);
        float ea = __expf(a - m), eb = __expf(b - m);
        float inv = 1.0f / (ea + eb);
        *(float2*)(out + (size_t)n * 2) = make_float2(ea * inv, eb * inv);
    }
}

// ---------------- fallback (R2 atomic path) --------------------------------
template <int F>
__global__ void scatter_kernel(const float* __restrict__ t,
                               const int* __restrict__ src,
                               const int* __restrict__ dst,
                               float* __restrict__ acc, int nE) {
    int tid = blockIdx.x * blockDim.x + threadIdx.x;
    int e = tid / F;
    if (e >= nE) return;
    int f = tid & (F - 1);
    atomicAdd(acc + (long)dst[e] * F + f, t[(long)src[e] * F + f]);
}

__global__ void softmax2_kernel(const float* __restrict__ h, float* __restrict__ out, int N) {
    int n = blockIdx.x * blockDim.x + threadIdx.x;
    if (n >= N) return;
    float a = h[2 * n], b = h[2 * n + 1];
    float m = fmaxf(a, b);
    float ea = __expf(a - m), eb = __expf(b - m);
    float inv = 1.0f / (ea + eb);
    out[2 * n] = ea * inv;
    out[2 * n + 1] = eb * inv;
}

extern "C" void kernel_launch(void* const* d_in, const int* in_sizes, int n_in,
                              void* d_out, int out_size, void* d_ws, size_t ws_size,
                              hipStream_t stream) {
    const float* z      = (const float*)d_in[0];
    const int*   ei     = (const int*)d_in[1];
    const float* Wrel1  = (const float*)d_in[2];
    const float* Wroot1 = (const float*)d_in[3];
    const float* b1     = (const float*)d_in[4];
    const float* Wrel2  = (const float*)d_in[5];
    const float* Wroot2 = (const float*)d_in[6];
    const float* b2     = (const float*)d_in[7];
    const float* Wrel3  = (const float*)d_in[8];
    const float* Wroot3 = (const float*)d_in[9];
    const float* b3     = (const float*)d_in[10];

    const int N  = in_sizes[0] / 64;   // 100000
    const int nE = in_sizes[1] / 2;    // 1600000
    const int* src = ei;
    const int* dst = ei + nE;
    const int NB = (N + RNODES - 1) / RNODES;   // 782
    const int C  = (nE + CH - 1) / CH;          // 391 chunks

    // ---- flat workspace layout (no aliasing; ~47 MB of workspace) ----
    char* wsb = (char*)d_ws;
    size_t off = 0;
    auto take = [&](size_t bytes) -> void* {
        void* p = (void*)(wsb + off);
        off = (off + bytes + 255) & ~(size_t)255;
        return p;
    };
    int*          chunkhist   = (int*)take((size_t)CMAX * NB_MAX * 4);
    int*          gtotal      = (int*)take((size_t)NB_MAX * 4);
    int*          bptr        = (int*)take((size_t)(NB_MAX + 1) * 4);
    unsigned int* records     = (unsigned int*)take((size_t)nE * 4);
    int*          rowptr      = (int*)take((size_t)(N + 1) * 4);
    int*          srcs_sorted = (int*)take((size_t)nE * 4);
    short*        t1          = (short*)take((size_t)N * 32 * 2);
    float*        s1          = (float*)take((size_t)N * 4);
    float*        h1          = (float*)take((size_t)N * 32 * 4);
    short*        t2          = (short*)take((size_t)N * 16 * 2);
    float*        s2          = (float*)take((size_t)N * 4);
    float*        h2          = (float*)take((size_t)N * 16 * 4);
    short*        t3          = (short*)take((size_t)N * 2 * 2);
    float*        s3          = (float*)take((size_t)N * 4);
    float*        h3          = (float*)take((size_t)N * 2 * 4);
    const size_t needed = off;

    const int B = 256;
    const int nodeBlocks = (N + B - 1) / B;
    const bool packOK = (N <= (1 << 17)) && (NB <= NB_MAX) && (C <= CMAX);

    if (ws_size >= needed && packOK) {
        // ---- build: zero-global-atomic deterministic CSR ----
        hist_chunked_kernel<<<C, 512, 0, stream>>>(dst, chunkhist, nE, NB);
        scan_chunkhist_kernel<<<NB, CMAX, 0, stream>>>(chunkhist, gtotal, C, NB);
        scan_buckets_kernel<<<1, NB_MAX, 0, stream>>>(gtotal, bptr, NB, nE);
        bucketize_det_kernel<<<C, 512, 0, stream>>>(src, dst, chunkhist, bptr, records, nE, NB);
        place_merge_kernel<<<NB, 512, 0, stream>>>(records, bptr, rowptr, srcs_sorted, N, nE, NB);

        // ---- Layer 1: 64 -> 32 ----
        linear_fused_q_kernel<64, 32, false><<<nodeBlocks, B, 0, stream>>>(
            z, Wrel1, Wroot1, b1, t1, s1, h1, N);
        gather_agg_q_kernel<32, false><<<((size_t)N * 16 + B - 1) / B, B, 0, stream>>>(
            t1, s1, rowptr, srcs_sorted, h1, h1, N);

        // ---- Layer 2: 32 -> 16 ----
        linear_fused_q_kernel<32, 16, true><<<nodeBlocks, B, 0, stream>>>(
            h1, Wrel2, Wroot2, b2, t2, s2, h2, N);
        gather_agg_q_kernel<16, false><<<((size_t)N * 8 + B - 1) / B, B, 0, stream>>>(
            t2, s2, rowptr, srcs_sorted, h2, h2, N);

        // ---- Layer 3: 16 -> 2, softmax fused ----
        linear_fused_q_kernel<16, 2, true><<<nodeBlocks, B, 0, stream>>>(
            h2, Wrel3, Wroot3, b3, t3, s3, h3, N);
        gather_agg_q_kernel<2, true><<<((size_t)N + B - 1) / B, B, 0, stream>>>(
            t3, s3, rowptr, srcs_sorted, h3, (float*)d_out, N);
    } else {
        // ---- fallback: R2 atomic-scatter path (all f32, ping-pong layout) ----
        float* regionA = (float*)d_ws;
        float* regionB = regionA + (size_t)N * 32;
        float* ft1 = regionA;
        float* fh1 = regionB;
        float* ft2 = regionA;
        float* fh2 = regionA + (size_t)N * 16;
        float* ft3 = regionB;
        float* fh3 = regionB + (size_t)N * 2;
        const dim3 linGrid(nodeBlocks, 2);
        linear2_kernel<64, 32, false><<<linGrid, B, 0, stream>>>(z, Wrel1, Wroot1, b1, ft1, fh1, N);
        scatter_kernel<32><<<((size_t)nE * 32 + B - 1) / B, B, 0, stream>>>(ft1, src, dst, fh1, nE);
        linear2_kernel<32, 16, true><<<linGrid, B, 0, stream>>>(fh1, Wrel2, Wroot2, b2, ft2, fh2, N);
        scatter_kernel<16><<<((size_t)nE * 16 + B - 1) / B, B, 0, stream>>>(ft2, src, dst, fh2, nE);
        linear2_kernel<16, 2, true><<<linGrid, B, 0, stream>>>(fh2, Wrel3, Wroot3, b3, ft3, fh3, N);
        scatter_kernel<2><<<((size_t)nE * 2 + B - 1) / B, B, 0, stream>>>(ft3, src, dst, fh3, nE);
        softmax2_kernel<<<nodeBlocks, B, 0, stream>>>(fh3, (float*)d_out, N);
    }
}

// Round 3
// 248.055 us; speedup vs baseline: 1.0739x; 1.0739x over previous
//
#include <hip/hip_runtime.h>

// 3-layer GraphConv (PyG) + softmax, 100k nodes, 1.6M edges, f32 in/out.
// R2: f32 global atomics ~306G/s scattered -> pull-gather wins.
// R5: two-phase placement fixed build; transform store-amp found (94us).
// R7: linear2 (scalar-path weights, register accs) fixed transform.
// R9: fully deterministic build (zero global atomics). gather32 = 44.5us.
// R10: staged gather unroll: no change (248us) -> gathers are L3-gather-
//      BYTES bound (gather32 = 205MB from L3 = 4.6 TB/s).
// R11: fp16 t-tables FAILED accuracy: 5.08e-2 > 2e-2.
// R12: row-scaled int16 t-tables PASS accuracy (absmax 3.9e-3) and the
//      gathers fell out of the top-5 -- but fusing rel+root spilled
//      (VGPR_Count=64 vs 64 f32 accumulators, occupancy 15%, VALU 14%,
//      linears 8->50us each). Net 266us.
// R13: revert linear to split rel/root passes (grid.y=2, 32 accs max, no
//      spill, 782 blocks) with int16 quant fused into the rel pass.

#define RNODES 128
#define NB_MAX 1024
#define CH 4096            // edges per chunk
#define CMAX 512           // max chunks (scan_chunkhist: one chunk/thread)

// ------- split linear: y=0: t=quant(x@Wrel) int16+scale; y=1: acc=x@Wroot+b
template <int Fin, int Fout, bool RELU>
__global__ void linear_q2_kernel(const float* __restrict__ x,
                                 const float* __restrict__ Wrel,
                                 const float* __restrict__ Wroot,
                                 const float* __restrict__ bias,
                                 short* __restrict__ t,
                                 float* __restrict__ tscale,
                                 float* __restrict__ acc, int N) {
    const bool rootTask = (blockIdx.y != 0);
    const float* __restrict__ W = rootTask ? Wroot : Wrel;

    int n = blockIdx.x * blockDim.x + threadIdx.x;
    if (n >= N) return;

    float o[Fout];
#pragma unroll
    for (int f = 0; f < Fout; ++f) o[f] = 0.f;

    const float* xr = x + (size_t)n * Fin;
#pragma unroll
    for (int k = 0; k < Fin; k += 4) {
        float4 v = *(const float4*)(xr + k);
        if (RELU) {
            v.x = fmaxf(v.x, 0.f); v.y = fmaxf(v.y, 0.f);
            v.z = fmaxf(v.z, 0.f); v.w = fmaxf(v.w, 0.f);
        }
        const float xv[4] = {v.x, v.y, v.z, v.w};
#pragma unroll
        for (int kk = 0; kk < 4; ++kk) {
            const float* wr = W + (size_t)(k + kk) * Fout;
#pragma unroll
            for (int f = 0; f < Fout; ++f)
                o[f] = fmaf(xv[kk], wr[f], o[f]);
        }
    }

    if (rootTask) {
        // --- root + bias -> acc (f32) ---
#pragma unroll
        for (int f = 0; f < Fout; ++f) o[f] += bias[f];
        float* arow = acc + (size_t)n * Fout;
        if constexpr (Fout >= 4) {
#pragma unroll
            for (int f = 0; f < Fout; f += 4)
                *(float4*)(arow + f) = make_float4(o[f], o[f+1], o[f+2], o[f+3]);
        } else {
            *(float2*)arow = make_float2(o[0], o[1]);
        }
    } else {
        // --- row-scaled int16 quantization of rel output (gathered table) ---
        float m = 0.f;
#pragma unroll
        for (int f = 0; f < Fout; ++f) m = fmaxf(m, fabsf(o[f]));
        const float inv = (m > 0.f) ? (32767.0f / m) : 0.f;
        tscale[n] = m * (1.0f / 32767.0f);

        short q[Fout];
#pragma unroll
        for (int f = 0; f < Fout; ++f) q[f] = (short)__float2int_rn(o[f] * inv);

        short* trow = t + (size_t)n * Fout;
        if constexpr (Fout >= 8) {
#pragma unroll
            for (int f = 0; f < Fout; f += 8)
                *(int4*)(trow + f) = *(const int4*)(q + f);    // 16B stores
        } else {
            *(int*)trow = (int)(unsigned short)q[0] | ((int)q[1] << 16);
        }
    }
}

// ---------------- legacy f32 linear (fallback path only) -------------------
template <int Fin, int Fout, bool RELU>
__global__ void linear2_kernel(const float* __restrict__ x,
                               const float* __restrict__ Wrel,
                               const float* __restrict__ Wroot,
                               const float* __restrict__ bias,
                               float* __restrict__ t,
                               float* __restrict__ acc, int N) {
    const bool rootTask = (blockIdx.y != 0);
    const float* __restrict__ W = rootTask ? Wroot : Wrel;
    float* __restrict__ outp    = rootTask ? acc : t;

    int n = blockIdx.x * blockDim.x + threadIdx.x;
    if (n >= N) return;

    float o[Fout];
#pragma unroll
    for (int f = 0; f < Fout; ++f) o[f] = 0.f;

    const float* xr = x + (size_t)n * Fin;
#pragma unroll
    for (int k = 0; k < Fin; k += 4) {
        float4 v = *(const float4*)(xr + k);
        if (RELU) {
            v.x = fmaxf(v.x, 0.f); v.y = fmaxf(v.y, 0.f);
            v.z = fmaxf(v.z, 0.f); v.w = fmaxf(v.w, 0.f);
        }
        const float xv[4] = {v.x, v.y, v.z, v.w};
#pragma unroll
        for (int kk = 0; kk < 4; ++kk) {
            const float* wr = W + (size_t)(k + kk) * Fout;
#pragma unroll
            for (int f = 0; f < Fout; ++f)
                o[f] = fmaf(xv[kk], wr[f], o[f]);
        }
    }
    if (rootTask) {
#pragma unroll
        for (int f = 0; f < Fout; ++f) o[f] += bias[f];
    }
    float* op = outp + (size_t)n * Fout;
    if constexpr (Fout >= 4) {
#pragma unroll
        for (int f = 0; f < Fout; f += 4)
            *(float4*)(op + f) = make_float4(o[f], o[f + 1], o[f + 2], o[f + 3]);
    } else {
        *(float2*)op = make_float2(o[0], o[1]);
    }
}

// ---------------- build step 1: per-chunk LDS histogram --------------------
__global__ void hist_chunked_kernel(const int* __restrict__ dst,
                                    int* __restrict__ chunkhist,
                                    int nE, int NB) {
    __shared__ int h[NB_MAX];
    const int c  = blockIdx.x;
    const int e0 = c * CH, e1 = min(e0 + CH, nE);
    for (int b = threadIdx.x; b < NB; b += blockDim.x) h[b] = 0;
    __syncthreads();
    for (int e = e0 + threadIdx.x; e < e1; e += blockDim.x)
        atomicAdd(&h[dst[e] >> 7], 1);
    __syncthreads();
    for (int b = threadIdx.x; b < NB; b += blockDim.x)
        chunkhist[(size_t)c * NB + b] = h[b];          // contiguous row flush
}

// ---------------- build step 2: column scan (per bucket over chunks) -------
__global__ void scan_chunkhist_kernel(int* __restrict__ chunkhist,
                                      int* __restrict__ gtotal,
                                      int C, int NB) {
    __shared__ int s[CMAX];
    const int b = blockIdx.x;
    const int t = threadIdx.x;
    int v = (t < C) ? chunkhist[(size_t)t * NB + b] : 0;
    s[t] = v;
    __syncthreads();
    for (int off = 1; off < CMAX; off <<= 1) {
        int u = (t >= off) ? s[t - off] : 0;
        __syncthreads();
        s[t] += u;
        __syncthreads();
    }
    if (t < C) chunkhist[(size_t)t * NB + b] = s[t] - v;   // exclusive
    if (t == CMAX - 1) gtotal[b] = s[t];                   // inclusive total
}

// ---------------- build step 3: bucket scan (single block) -----------------
__global__ void scan_buckets_kernel(const int* __restrict__ gtotal,
                                    int* __restrict__ bptr, int NB, int nE) {
    __shared__ int s[NB_MAX];
    int t = threadIdx.x;
    int own = (t < NB) ? gtotal[t] : 0;
    s[t] = own;
    __syncthreads();
    for (int off = 1; off < NB_MAX; off <<= 1) {
        int v = (t >= off) ? s[t - off] : 0;
        __syncthreads();
        s[t] += v;
        __syncthreads();
    }
    if (t < NB) bptr[t] = s[t] - own;
    if (t == 0) bptr[NB] = nE;
}

// ---------------- build step 4: deterministic placement --------------------
__global__ void bucketize_det_kernel(const int* __restrict__ src,
                                     const int* __restrict__ dst,
                                     const int* __restrict__ chunkpre,
                                     const int* __restrict__ bptr,
                                     unsigned int* __restrict__ records,
                                     int nE, int NB) {
    __shared__ int lcur[NB_MAX];
    const int c  = blockIdx.x;
    const int e0 = c * CH, e1 = min(e0 + CH, nE);
    for (int b = threadIdx.x; b < NB; b += blockDim.x)
        lcur[b] = bptr[b] + chunkpre[(size_t)c * NB + b];
    __syncthreads();
    for (int e = e0 + threadIdx.x; e < e1; e += blockDim.x) {
        int d = dst[e];
        int b = d >> 7;
        int pos = atomicAdd(&lcur[b], 1);                  // LDS-only atomic
        records[pos] = (unsigned int)src[e] | ((unsigned int)(d & 127) << 17);
    }
}

// ---------------- build step 5: per-bucket hist+scan+rowptr+place ----------
__global__ void place_merge_kernel(const unsigned int* __restrict__ records,
                                   const int* __restrict__ bptr,
                                   int* __restrict__ rowptr,
                                   int* __restrict__ srcs_sorted,
                                   int N, int nE, int NB) {
    __shared__ int hist[RNODES];
    __shared__ int s[RNODES];
    __shared__ int lcur[RNODES];
    const int b    = blockIdx.x;
    const int base = b * RNODES;
    const int nn   = min(RNODES, N - base);
    const int beg  = bptr[b], end = bptr[b + 1];
    const int t    = threadIdx.x;

    if (t < RNODES) hist[t] = 0;
    __syncthreads();
    for (int i = beg + t; i < end; i += blockDim.x)
        atomicAdd(&hist[records[i] >> 17], 1);
    __syncthreads();

    if (t < RNODES) s[t] = hist[t];
    __syncthreads();
    for (int off = 1; off < RNODES; off <<= 1) {
        int v = (t < RNODES && t >= off) ? s[t - off] : 0;
        __syncthreads();
        if (t < RNODES && t >= off) s[t] += v;
        __syncthreads();
    }
    if (t < nn) {
        int ex = beg + s[t] - hist[t];
        rowptr[base + t] = ex;
        lcur[t] = ex;
    }
    if (b == NB - 1 && t == 0) rowptr[N] = nE;
    __syncthreads();

    for (int i = beg + t; i < end; i += blockDim.x) {
        unsigned int rec = records[i];
        int pos = atomicAdd(&lcur[rec >> 17], 1);
        srcs_sorted[pos] = (int)(rec & 0x1FFFFu);
    }
}

// ------- pull aggregation: int16 rows + per-row scale, staged 8/1 ----------
// F>=4: F/2 lanes per node, each lane owns one short2 (2 features).
// F==2: 1 lane per node.
template <int F, bool SOFTMAX>
__global__ void gather_agg_q_kernel(const short* __restrict__ t,
                                    const float* __restrict__ tscale,
                                    const int* __restrict__ rowptr,
                                    const int* __restrict__ srcs,
                                    const float* __restrict__ rootacc,
                                    float* __restrict__ out, int N) {
    constexpr int P = (F >= 4) ? (F / 2) : 1;   // lanes per node
    constexpr int S = F / 2;                    // row stride in short2 (ints)
    int tid = blockIdx.x * blockDim.x + threadIdx.x;
    int n  = (P == 1) ? tid : (tid / P);
    int fp = (P == 1) ? 0   : (tid & (P - 1));
    if (n >= N) return;

    const int* tp = (const int*)t;              // short2 viewed as int
    int beg = rowptr[n], end = rowptr[n + 1];
    float sx = 0.f, sy = 0.f;
    int e = beg;
    // stage: 8 concurrent edge gathers (mean degree ~16 -> two batches)
    for (; e + 8 <= end; e += 8) {
        int s[8];
#pragma unroll
        for (int u = 0; u < 8; ++u) s[u] = srcs[e + u];
        int q[8]; float sc[8];
#pragma unroll
        for (int u = 0; u < 8; ++u) {
            q[u]  = tp[s[u] * S + fp];
            sc[u] = tscale[s[u]];
        }
#pragma unroll
        for (int u = 0; u < 8; ++u) {
            float lo = (float)((short)(q[u] & 0xFFFF));
            float hi = (float)(q[u] >> 16);
            sx = fmaf(sc[u], lo, sx);
            sy = fmaf(sc[u], hi, sy);
        }
    }
    // tail (<=7)
    for (; e < end; ++e) {
        int s0 = srcs[e];
        int qv = tp[s0 * S + fp];
        float sc = tscale[s0];
        sx = fmaf(sc, (float)((short)(qv & 0xFFFF)), sx);
        sy = fmaf(sc, (float)(qv >> 16), sy);
    }

    const float2 r0 = *(const float2*)(rootacc + (size_t)n * F + 2 * fp);
    float a = r0.x + sx, b = r0.y + sy;
    if (!SOFTMAX) {
        *(float2*)(out + (size_t)n * F + 2 * fp) = make_float2(a, b);
    } else {
        float m = fmaxf(a, b);
        float ea = __expf(a - m), eb = __expf(b - m);
        float inv = 1.0f / (ea + eb);
        *(float2*)(out + (size_t)n * 2) = make_float2(ea * inv, eb * inv);
    }
}

// ---------------- fallback (R2 atomic path) --------------------------------
template <int F>
__global__ void scatter_kernel(const float* __restrict__ t,
                               const int* __restrict__ src,
                               const int* __restrict__ dst,
                               float* __restrict__ acc, int nE) {
    int tid = blockIdx.x * blockDim.x + threadIdx.x;
    int e = tid / F;
    if (e >= nE) return;
    int f = tid & (F - 1);
    atomicAdd(acc + (long)dst[e] * F + f, t[(long)src[e] * F + f]);
}

__global__ void softmax2_kernel(const float* __restrict__ h, float* __restrict__ out, int N) {
    int n = blockIdx.x * blockDim.x + threadIdx.x;
    if (n >= N) return;
    float a = h[2 * n], b = h[2 * n + 1];
    float m = fmaxf(a, b);
    float ea = __expf(a - m), eb = __expf(b - m);
    float inv = 1.0f / (ea + eb);
    out[2 * n] = ea * inv;
    out[2 * n + 1] = eb * inv;
}

extern "C" void kernel_launch(void* const* d_in, const int* in_sizes, int n_in,
                              void* d_out, int out_size, void* d_ws, size_t ws_size,
                              hipStream_t stream) {
    const float* z      = (const float*)d_in[0];
    const int*   ei     = (const int*)d_in[1];
    const float* Wrel1  = (const float*)d_in[2];
    const float* Wroot1 = (const float*)d_in[3];
    const float* b1     = (const float*)d_in[4];
    const float* Wrel2  = (const float*)d_in[5];
    const float* Wroot2 = (const float*)d_in[6];
    const float* b2     = (const float*)d_in[7];
    const float* Wrel3  = (const float*)d_in[8];
    const float* Wroot3 = (const float*)d_in[9];
    const float* b3     = (const float*)d_in[10];

    const int N  = in_sizes[0] / 64;   // 100000
    const int nE = in_sizes[1] / 2;    // 1600000
    const int* src = ei;
    const int* dst = ei + nE;
    const int NB = (N + RNODES - 1) / RNODES;   // 782
    const int C  = (nE + CH - 1) / CH;          // 391 chunks

    // ---- flat workspace layout (no aliasing; ~47 MB of workspace) ----
    char* wsb = (char*)d_ws;
    size_t off = 0;
    auto take = [&](size_t bytes) -> void* {
        void* p = (void*)(wsb + off);
        off = (off + bytes + 255) & ~(size_t)255;
        return p;
    };
    int*          chunkhist   = (int*)take((size_t)CMAX * NB_MAX * 4);
    int*          gtotal      = (int*)take((size_t)NB_MAX * 4);
    int*          bptr        = (int*)take((size_t)(NB_MAX + 1) * 4);
    unsigned int* records     = (unsigned int*)take((size_t)nE * 4);
    int*          rowptr      = (int*)take((size_t)(N + 1) * 4);
    int*          srcs_sorted = (int*)take((size_t)nE * 4);
    short*        t1          = (short*)take((size_t)N * 32 * 2);
    float*        s1          = (float*)take((size_t)N * 4);
    float*        h1          = (float*)take((size_t)N * 32 * 4);
    short*        t2          = (short*)take((size_t)N * 16 * 2);
    float*        s2          = (float*)take((size_t)N * 4);
    float*        h2          = (float*)take((size_t)N * 16 * 4);
    short*        t3          = (short*)take((size_t)N * 2 * 2);
    float*        s3          = (float*)take((size_t)N * 4);
    float*        h3          = (float*)take((size_t)N * 2 * 4);
    const size_t needed = off;

    const int B = 256;
    const int nodeBlocks = (N + B - 1) / B;
    const dim3 linGrid(nodeBlocks, 2);       // y=0: rel(quant)->t, y=1: root+b->acc
    const bool packOK = (N <= (1 << 17)) && (NB <= NB_MAX) && (C <= CMAX);

    if (ws_size >= needed && packOK) {
        // ---- build: zero-global-atomic deterministic CSR ----
        hist_chunked_kernel<<<C, 512, 0, stream>>>(dst, chunkhist, nE, NB);
        scan_chunkhist_kernel<<<NB, CMAX, 0, stream>>>(chunkhist, gtotal, C, NB);
        scan_buckets_kernel<<<1, NB_MAX, 0, stream>>>(gtotal, bptr, NB, nE);
        bucketize_det_kernel<<<C, 512, 0, stream>>>(src, dst, chunkhist, bptr, records, nE, NB);
        place_merge_kernel<<<NB, 512, 0, stream>>>(records, bptr, rowptr, srcs_sorted, N, nE, NB);

        // ---- Layer 1: 64 -> 32 ----
        linear_q2_kernel<64, 32, false><<<linGrid, B, 0, stream>>>(
            z, Wrel1, Wroot1, b1, t1, s1, h1, N);
        gather_agg_q_kernel<32, false><<<((size_t)N * 16 + B - 1) / B, B, 0, stream>>>(
            t1, s1, rowptr, srcs_sorted, h1, h1, N);

        // ---- Layer 2: 32 -> 16 ----
        linear_q2_kernel<32, 16, true><<<linGrid, B, 0, stream>>>(
            h1, Wrel2, Wroot2, b2, t2, s2, h2, N);
        gather_agg_q_kernel<16, false><<<((size_t)N * 8 + B - 1) / B, B, 0, stream>>>(
            t2, s2, rowptr, srcs_sorted, h2, h2, N);

        // ---- Layer 3: 16 -> 2, softmax fused ----
        linear_q2_kernel<16, 2, true><<<linGrid, B, 0, stream>>>(
            h2, Wrel3, Wroot3, b3, t3, s3, h3, N);
        gather_agg_q_kernel<2, true><<<((size_t)N + B - 1) / B, B, 0, stream>>>(
            t3, s3, rowptr, srcs_sorted, h3, (float*)d_out, N);
    } else {
        // ---- fallback: R2 atomic-scatter path (all f32, ping-pong layout) ----
        float* regionA = (float*)d_ws;
        float* regionB = regionA + (size_t)N * 32;
        float* ft1 = regionA;
        float* fh1 = regionB;
        float* ft2 = regionA;
        float* fh2 = regionA + (size_t)N * 16;
        float* ft3 = regionB;
        float* fh3 = regionB + (size_t)N * 2;
        linear2_kernel<64, 32, false><<<linGrid, B, 0, stream>>>(z, Wrel1, Wroot1, b1, ft1, fh1, N);
        scatter_kernel<32><<<((size_t)nE * 32 + B - 1) / B, B, 0, stream>>>(ft1, src, dst, fh1, nE);
        linear2_kernel<32, 16, true><<<linGrid, B, 0, stream>>>(fh1, Wrel2, Wroot2, b2, ft2, fh2, N);
        scatter_kernel<16><<<((size_t)nE * 16 + B - 1) / B, B, 0, stream>>>(ft2, src, dst, fh2, nE);
        linear2_kernel<16, 2, true><<<linGrid, B, 0, stream>>>(fh2, Wrel3, Wroot3, b3, ft3, fh3, N);
        scatter_kernel<2><<<((size_t)nE * 2 + B - 1) / B, B, 0, stream>>>(ft3, src, dst, fh3, nE);
        softmax2_kernel<<<nodeBlocks, B, 0, stream>>>(fh3, (float*)d_out, N);
    }
}

// Round 4
// 243.033 us; speedup vs baseline: 1.0961x; 1.0207x over previous
//
#include <hip/hip_runtime.h>

// 3-layer GraphConv (PyG) + softmax, 100k nodes, 1.6M edges, f32 in/out.
// R2: f32 global atomics ~306G/s scattered -> pull-gather wins.
// R5: two-phase placement fixed build; transform store-amp found (94us).
// R9: fully deterministic build (zero global atomics). gather32 = 44.5us.
// R10: staged gather unroll: NULL -> not latency-bound.
// R11: fp16 t-tables FAILED accuracy: 5.08e-2 > 2e-2.
// R12: row-scaled int16 t PASSES accuracy, but fused linear spilled (266us).
// R13: split linears fixed (248us) -- int16 gather delta = NULL. Both nulls
//      + rate math (3.2M reqs / 44.5us = 72G/s = 4.6TB/s / 64B) say gathers
//      are L2/L3 REQUEST-RATE bound at 2 reqs/edge (row line + scale line).
// R14: put the scale in the SAME 64B line as the row:
//      L2: 64B rows {q[16] | f32 scale | pad} -> scale load is L1-hit.
//      L3: 8B rows {q0,q1,scale} int2, 4 lanes/node + shfl reduce.
//      L1: UNCHANGED (control: 64B row is full; stays 2 req/edge).
//      Predict gather16/gather2 44->23us each, gather32 flat, total ~205us.

#define RNODES 128
#define NB_MAX 1024
#define CH 4096            // edges per chunk
#define CMAX 512           // max chunks (scan_chunkhist: one chunk/thread)

// ------- split linear: y=0: t=quant(x@Wrel) int16 (+scale); y=1: acc=x@Wroot+b
// Fout==32: t stride 32 shorts, scale in separate tscale[] (legacy, L1 control)
// Fout==16: t stride 32 shorts (64B rows): {q[16] | f32 scale @byte32 | pad}
// Fout==2 : t stride 4 shorts (8B rows): {q0,q1 | f32 scale}
template <int Fin, int Fout, bool RELU>
__global__ void linear_q2_kernel(const float* __restrict__ x,
                                 const float* __restrict__ Wrel,
                                 const float* __restrict__ Wroot,
                                 const float* __restrict__ bias,
                                 short* __restrict__ t,
                                 float* __restrict__ tscale,
                                 float* __restrict__ acc, int N) {
    const bool rootTask = (blockIdx.y != 0);
    const float* __restrict__ W = rootTask ? Wroot : Wrel;

    int n = blockIdx.x * blockDim.x + threadIdx.x;
    if (n >= N) return;

    float o[Fout];
#pragma unroll
    for (int f = 0; f < Fout; ++f) o[f] = 0.f;

    const float* xr = x + (size_t)n * Fin;
#pragma unroll
    for (int k = 0; k < Fin; k += 4) {
        float4 v = *(const float4*)(xr + k);
        if (RELU) {
            v.x = fmaxf(v.x, 0.f); v.y = fmaxf(v.y, 0.f);
            v.z = fmaxf(v.z, 0.f); v.w = fmaxf(v.w, 0.f);
        }
        const float xv[4] = {v.x, v.y, v.z, v.w};
#pragma unroll
        for (int kk = 0; kk < 4; ++kk) {
            const float* wr = W + (size_t)(k + kk) * Fout;
#pragma unroll
            for (int f = 0; f < Fout; ++f)
                o[f] = fmaf(xv[kk], wr[f], o[f]);
        }
    }

    if (rootTask) {
        // --- root + bias -> acc (f32) ---
#pragma unroll
        for (int f = 0; f < Fout; ++f) o[f] += bias[f];
        float* arow = acc + (size_t)n * Fout;
        if constexpr (Fout >= 4) {
#pragma unroll
            for (int f = 0; f < Fout; f += 4)
                *(float4*)(arow + f) = make_float4(o[f], o[f+1], o[f+2], o[f+3]);
        } else {
            *(float2*)arow = make_float2(o[0], o[1]);
        }
    } else {
        // --- row-scaled int16 quantization of rel output (gathered table) ---
        float m = 0.f;
#pragma unroll
        for (int f = 0; f < Fout; ++f) m = fmaxf(m, fabsf(o[f]));
        const float inv = (m > 0.f) ? (32767.0f / m) : 0.f;
        const float sc  = m * (1.0f / 32767.0f);

        short q[Fout];
#pragma unroll
        for (int f = 0; f < Fout; ++f) q[f] = (short)__float2int_rn(o[f] * inv);

        if constexpr (Fout == 32) {
            // legacy layout: 64B data row + separate scale array (L1 control)
            tscale[n] = sc;
            short* trow = t + (size_t)n * 32;
#pragma unroll
            for (int f = 0; f < 32; f += 8)
                *(int4*)(trow + f) = *(const int4*)(q + f);    // 16B stores
        } else if constexpr (Fout == 16) {
            // 64B row: {q[16] (32B) | f32 scale | 28B pad}
            short* trow = t + (size_t)n * 32;                  // stride 64B
            *(int4*)(trow)     = *(const int4*)(q);
            *(int4*)(trow + 8) = *(const int4*)(q + 8);
            ((float*)trow)[8]  = sc;                           // byte offset 32
        } else {
            // 8B row: {q0,q1 | f32 scale}
            int2 r;
            r.x = (int)(unsigned short)q[0] | ((int)q[1] << 16);
            r.y = __float_as_int(sc);
            *(int2*)(t + (size_t)n * 4) = r;
        }
    }
}

// ---------------- legacy f32 linear (fallback path only) -------------------
template <int Fin, int Fout, bool RELU>
__global__ void linear2_kernel(const float* __restrict__ x,
                               const float* __restrict__ Wrel,
                               const float* __restrict__ Wroot,
                               const float* __restrict__ bias,
                               float* __restrict__ t,
                               float* __restrict__ acc, int N) {
    const bool rootTask = (blockIdx.y != 0);
    const float* __restrict__ W = rootTask ? Wroot : Wrel;
    float* __restrict__ outp    = rootTask ? acc : t;

    int n = blockIdx.x * blockDim.x + threadIdx.x;
    if (n >= N) return;

    float o[Fout];
#pragma unroll
    for (int f = 0; f < Fout; ++f) o[f] = 0.f;

    const float* xr = x + (size_t)n * Fin;
#pragma unroll
    for (int k = 0; k < Fin; k += 4) {
        float4 v = *(const float4*)(xr + k);
        if (RELU) {
            v.x = fmaxf(v.x, 0.f); v.y = fmaxf(v.y, 0.f);
            v.z = fmaxf(v.z, 0.f); v.w = fmaxf(v.w, 0.f);
        }
        const float xv[4] = {v.x, v.y, v.z, v.w};
#pragma unroll
        for (int kk = 0; kk < 4; ++kk) {
            const float* wr = W + (size_t)(k + kk) * Fout;
#pragma unroll
            for (int f = 0; f < Fout; ++f)
                o[f] = fmaf(xv[kk], wr[f], o[f]);
        }
    }
    if (rootTask) {
#pragma unroll
        for (int f = 0; f < Fout; ++f) o[f] += bias[f];
    }
    float* op = outp + (size_t)n * Fout;
    if constexpr (Fout >= 4) {
#pragma unroll
        for (int f = 0; f < Fout; f += 4)
            *(float4*)(op + f) = make_float4(o[f], o[f + 1], o[f + 2], o[f + 3]);
    } else {
        *(float2*)op = make_float2(o[0], o[1]);
    }
}

// ---------------- build step 1: per-chunk LDS histogram --------------------
__global__ void hist_chunked_kernel(const int* __restrict__ dst,
                                    int* __restrict__ chunkhist,
                                    int nE, int NB) {
    __shared__ int h[NB_MAX];
    const int c  = blockIdx.x;
    const int e0 = c * CH, e1 = min(e0 + CH, nE);
    for (int b = threadIdx.x; b < NB; b += blockDim.x) h[b] = 0;
    __syncthreads();
    for (int e = e0 + threadIdx.x; e < e1; e += blockDim.x)
        atomicAdd(&h[dst[e] >> 7], 1);
    __syncthreads();
    for (int b = threadIdx.x; b < NB; b += blockDim.x)
        chunkhist[(size_t)c * NB + b] = h[b];          // contiguous row flush
}

// ---------------- build step 2: column scan (per bucket over chunks) -------
__global__ void scan_chunkhist_kernel(int* __restrict__ chunkhist,
                                      int* __restrict__ gtotal,
                                      int C, int NB) {
    __shared__ int s[CMAX];
    const int b = blockIdx.x;
    const int t = threadIdx.x;
    int v = (t < C) ? chunkhist[(size_t)t * NB + b] : 0;
    s[t] = v;
    __syncthreads();
    for (int off = 1; off < CMAX; off <<= 1) {
        int u = (t >= off) ? s[t - off] : 0;
        __syncthreads();
        s[t] += u;
        __syncthreads();
    }
    if (t < C) chunkhist[(size_t)t * NB + b] = s[t] - v;   // exclusive
    if (t == CMAX - 1) gtotal[b] = s[t];                   // inclusive total
}

// ---------------- build step 3: bucket scan (single block) -----------------
__global__ void scan_buckets_kernel(const int* __restrict__ gtotal,
                                    int* __restrict__ bptr, int NB, int nE) {
    __shared__ int s[NB_MAX];
    int t = threadIdx.x;
    int own = (t < NB) ? gtotal[t] : 0;
    s[t] = own;
    __syncthreads();
    for (int off = 1; off < NB_MAX; off <<= 1) {
        int v = (t >= off) ? s[t - off] : 0;
        __syncthreads();
        s[t] += v;
        __syncthreads();
    }
    if (t < NB) bptr[t] = s[t] - own;
    if (t == 0) bptr[NB] = nE;
}

// ---------------- build step 4: deterministic placement --------------------
__global__ void bucketize_det_kernel(const int* __restrict__ src,
                                     const int* __restrict__ dst,
                                     const int* __restrict__ chunkpre,
                                     const int* __restrict__ bptr,
                                     unsigned int* __restrict__ records,
                                     int nE, int NB) {
    __shared__ int lcur[NB_MAX];
    const int c  = blockIdx.x;
    const int e0 = c * CH, e1 = min(e0 + CH, nE);
    for (int b = threadIdx.x; b < NB; b += blockDim.x)
        lcur[b] = bptr[b] + chunkpre[(size_t)c * NB + b];
    __syncthreads();
    for (int e = e0 + threadIdx.x; e < e1; e += blockDim.x) {
        int d = dst[e];
        int b = d >> 7;
        int pos = atomicAdd(&lcur[b], 1);                  // LDS-only atomic
        records[pos] = (unsigned int)src[e] | ((unsigned int)(d & 127) << 17);
    }
}

// ---------------- build step 5: per-bucket hist+scan+rowptr+place ----------
__global__ void place_merge_kernel(const unsigned int* __restrict__ records,
                                   const int* __restrict__ bptr,
                                   int* __restrict__ rowptr,
                                   int* __restrict__ srcs_sorted,
                                   int N, int nE, int NB) {
    __shared__ int hist[RNODES];
    __shared__ int s[RNODES];
    __shared__ int lcur[RNODES];
    const int b    = blockIdx.x;
    const int base = b * RNODES;
    const int nn   = min(RNODES, N - base);
    const int beg  = bptr[b], end = bptr[b + 1];
    const int t    = threadIdx.x;

    if (t < RNODES) hist[t] = 0;
    __syncthreads();
    for (int i = beg + t; i < end; i += blockDim.x)
        atomicAdd(&hist[records[i] >> 17], 1);
    __syncthreads();

    if (t < RNODES) s[t] = hist[t];
    __syncthreads();
    for (int off = 1; off < RNODES; off <<= 1) {
        int v = (t < RNODES && t >= off) ? s[t - off] : 0;
        __syncthreads();
        if (t < RNODES && t >= off) s[t] += v;
        __syncthreads();
    }
    if (t < nn) {
        int ex = beg + s[t] - hist[t];
        rowptr[base + t] = ex;
        lcur[t] = ex;
    }
    if (b == NB - 1 && t == 0) rowptr[N] = nE;
    __syncthreads();

    for (int i = beg + t; i < end; i += blockDim.x) {
        unsigned int rec = records[i];
        int pos = atomicAdd(&lcur[rec >> 17], 1);
        srcs_sorted[pos] = (int)(rec & 0x1FFFFu);
    }
}

// ------- L1 gather (CONTROL, unchanged): int16 rows + separate scale -------
// F=32: 16 lanes/node, each owns one short2 (2 features). 2 reqs/edge.
template <int F, bool SOFTMAX>
__global__ void gather_agg_q_kernel(const short* __restrict__ t,
                                    const float* __restrict__ tscale,
                                    const int* __restrict__ rowptr,
                                    const int* __restrict__ srcs,
                                    const float* __restrict__ rootacc,
                                    float* __restrict__ out, int N) {
    constexpr int P = (F >= 4) ? (F / 2) : 1;   // lanes per node
    constexpr int S = F / 2;                    // row stride in short2 (ints)
    int tid = blockIdx.x * blockDim.x + threadIdx.x;
    int n  = (P == 1) ? tid : (tid / P);
    int fp = (P == 1) ? 0   : (tid & (P - 1));
    if (n >= N) return;

    const int* tp = (const int*)t;              // short2 viewed as int
    int beg = rowptr[n], end = rowptr[n + 1];
    float sx = 0.f, sy = 0.f;
    int e = beg;
    for (; e + 8 <= end; e += 8) {
        int s[8];
#pragma unroll
        for (int u = 0; u < 8; ++u) s[u] = srcs[e + u];
        int q[8]; float sc[8];
#pragma unroll
        for (int u = 0; u < 8; ++u) {
            q[u]  = tp[s[u] * S + fp];
            sc[u] = tscale[s[u]];
        }
#pragma unroll
        for (int u = 0; u < 8; ++u) {
            float lo = (float)((short)(q[u] & 0xFFFF));
            float hi = (float)(q[u] >> 16);
            sx = fmaf(sc[u], lo, sx);
            sy = fmaf(sc[u], hi, sy);
        }
    }
    for (; e < end; ++e) {
        int s0 = srcs[e];
        int qv = tp[s0 * S + fp];
        float sc = tscale[s0];
        sx = fmaf(sc, (float)((short)(qv & 0xFFFF)), sx);
        sy = fmaf(sc, (float)(qv >> 16), sy);
    }

    const float2 r0 = *(const float2*)(rootacc + (size_t)n * F + 2 * fp);
    float a = r0.x + sx, b = r0.y + sy;
    if (!SOFTMAX) {
        *(float2*)(out + (size_t)n * F + 2 * fp) = make_float2(a, b);
    } else {
        float m = fmaxf(a, b);
        float ea = __expf(a - m), eb = __expf(b - m);
        float inv = 1.0f / (ea + eb);
        *(float2*)(out + (size_t)n * 2) = make_float2(ea * inv, eb * inv);
    }
}

// ------- L2 gather: 64B rows {q[16] | scale | pad}, scale L1-hit -----------
// 8 lanes/node; 1 line req/edge (scale rides the same 64B line).
__global__ void gather16_inl_kernel(const short* __restrict__ t,
                                    const int* __restrict__ rowptr,
                                    const int* __restrict__ srcs,
                                    const float* __restrict__ rootacc,
                                    float* __restrict__ out, int N) {
    int tid = blockIdx.x * blockDim.x + threadIdx.x;
    int n  = tid >> 3;
    int fp = tid & 7;
    if (n >= N) return;

    const int* tp = (const int*)t;              // 16 ints per row (64B)
    int beg = rowptr[n], end = rowptr[n + 1];
    float sx = 0.f, sy = 0.f;
    int e = beg;
    for (; e + 8 <= end; e += 8) {
        int s[8];
#pragma unroll
        for (int u = 0; u < 8; ++u) s[u] = srcs[e + u];
        int q[8]; float sc[8];
#pragma unroll
        for (int u = 0; u < 8; ++u) {
            const int* row = tp + (size_t)s[u] * 16;
            q[u]  = row[fp];                           // line request
            sc[u] = __int_as_float(row[8]);            // same line: L1 hit
        }
#pragma unroll
        for (int u = 0; u < 8; ++u) {
            sx = fmaf(sc[u], (float)((short)(q[u] & 0xFFFF)), sx);
            sy = fmaf(sc[u], (float)(q[u] >> 16), sy);
        }
    }
    for (; e < end; ++e) {
        const int* row = tp + (size_t)srcs[e] * 16;
        int qv = row[fp];
        float sc = __int_as_float(row[8]);
        sx = fmaf(sc, (float)((short)(qv & 0xFFFF)), sx);
        sy = fmaf(sc, (float)(qv >> 16), sy);
    }

    const float2 r0 = *(const float2*)(rootacc + (size_t)n * 16 + 2 * fp);
    *(float2*)(out + (size_t)n * 16 + 2 * fp) = make_float2(r0.x + sx, r0.y + sy);
}

// ------- L3 gather: 8B rows {q0,q1 | scale} int2, 4 lanes/node -------------
// Edge-parallel across 4 lanes + shfl reduce; softmax fused. 1 req/edge.
__global__ void gather2_inl_kernel(const short* __restrict__ t,
                                   const int* __restrict__ rowptr,
                                   const int* __restrict__ srcs,
                                   const float* __restrict__ rootacc,
                                   float* __restrict__ out, int N) {
    int tid = blockIdx.x * blockDim.x + threadIdx.x;
    int n  = tid >> 2;
    int fp = tid & 3;
    if (n >= N) return;

    const int2* tp = (const int2*)t;            // 8B rows
    int beg = rowptr[n], end = rowptr[n + 1];
    float sx = 0.f, sy = 0.f;
    int e = beg + fp;
    // 4 edges in flight per lane (16 across the node's 4 lanes)
    for (; e + 12 < end; e += 16) {
        int s0 = srcs[e], s1 = srcs[e + 4], s2 = srcs[e + 8], s3 = srcs[e + 12];
        int2 r0 = tp[s0], r1 = tp[s1], r2 = tp[s2], r3 = tp[s3];
        sx = fmaf(__int_as_float(r0.y), (float)((short)(r0.x & 0xFFFF)), sx);
        sy = fmaf(__int_as_float(r0.y), (float)(r0.x >> 16), sy);
        sx = fmaf(__int_as_float(r1.y), (float)((short)(r1.x & 0xFFFF)), sx);
        sy = fmaf(__int_as_float(r1.y), (float)(r1.x >> 16), sy);
        sx = fmaf(__int_as_float(r2.y), (float)((short)(r2.x & 0xFFFF)), sx);
        sy = fmaf(__int_as_float(r2.y), (float)(r2.x >> 16), sy);
        sx = fmaf(__int_as_float(r3.y), (float)((short)(r3.x & 0xFFFF)), sx);
        sy = fmaf(__int_as_float(r3.y), (float)(r3.x >> 16), sy);
    }
    for (; e < end; e += 4) {
        int2 r = tp[srcs[e]];
        sx = fmaf(__int_as_float(r.y), (float)((short)(r.x & 0xFFFF)), sx);
        sy = fmaf(__int_as_float(r.y), (float)(r.x >> 16), sy);
    }
    // reduce across the node's 4 consecutive lanes
    sx += __shfl_xor(sx, 1, 64); sy += __shfl_xor(sy, 1, 64);
    sx += __shfl_xor(sx, 2, 64); sy += __shfl_xor(sy, 2, 64);

    if (fp == 0) {
        const float2 r0 = *(const float2*)(rootacc + (size_t)n * 2);
        float a = r0.x + sx, b = r0.y + sy;
        float m = fmaxf(a, b);
        float ea = __expf(a - m), eb = __expf(b - m);
        float inv = 1.0f / (ea + eb);
        *(float2*)(out + (size_t)n * 2) = make_float2(ea * inv, eb * inv);
    }
}

// ---------------- fallback (R2 atomic path) --------------------------------
template <int F>
__global__ void scatter_kernel(const float* __restrict__ t,
                               const int* __restrict__ src,
                               const int* __restrict__ dst,
                               float* __restrict__ acc, int nE) {
    int tid = blockIdx.x * blockDim.x + threadIdx.x;
    int e = tid / F;
    if (e >= nE) return;
    int f = tid & (F - 1);
    atomicAdd(acc + (long)dst[e] * F + f, t[(long)src[e] * F + f]);
}

__global__ void softmax2_kernel(const float* __restrict__ h, float* __restrict__ out, int N) {
    int n = blockIdx.x * blockDim.x + threadIdx.x;
    if (n >= N) return;
    float a = h[2 * n], b = h[2 * n + 1];
    float m = fmaxf(a, b);
    float ea = __expf(a - m), eb = __expf(b - m);
    float inv = 1.0f / (ea + eb);
    out[2 * n] = ea * inv;
    out[2 * n + 1] = eb * inv;
}

extern "C" void kernel_launch(void* const* d_in, const int* in_sizes, int n_in,
                              void* d_out, int out_size, void* d_ws, size_t ws_size,
                              hipStream_t stream) {
    const float* z      = (const float*)d_in[0];
    const int*   ei     = (const int*)d_in[1];
    const float* Wrel1  = (const float*)d_in[2];
    const float* Wroot1 = (const float*)d_in[3];
    const float* b1     = (const float*)d_in[4];
    const float* Wrel2  = (const float*)d_in[5];
    const float* Wroot2 = (const float*)d_in[6];
    const float* b2     = (const float*)d_in[7];
    const float* Wrel3  = (const float*)d_in[8];
    const float* Wroot3 = (const float*)d_in[9];
    const float* b3     = (const float*)d_in[10];

    const int N  = in_sizes[0] / 64;   // 100000
    const int nE = in_sizes[1] / 2;    // 1600000
    const int* src = ei;
    const int* dst = ei + nE;
    const int NB = (N + RNODES - 1) / RNODES;   // 782
    const int C  = (nE + CH - 1) / CH;          // 391 chunks

    // ---- flat workspace layout (no aliasing) ----
    char* wsb = (char*)d_ws;
    size_t off = 0;
    auto take = [&](size_t bytes) -> void* {
        void* p = (void*)(wsb + off);
        off = (off + bytes + 255) & ~(size_t)255;
        return p;
    };
    int*          chunkhist   = (int*)take((size_t)CMAX * NB_MAX * 4);
    int*          gtotal      = (int*)take((size_t)NB_MAX * 4);
    int*          bptr        = (int*)take((size_t)(NB_MAX + 1) * 4);
    unsigned int* records     = (unsigned int*)take((size_t)nE * 4);
    int*          rowptr      = (int*)take((size_t)(N + 1) * 4);
    int*          srcs_sorted = (int*)take((size_t)nE * 4);
    short*        t1          = (short*)take((size_t)N * 32 * 2);   // 64B rows
    float*        s1          = (float*)take((size_t)N * 4);        // L1 scale
    float*        h1          = (float*)take((size_t)N * 32 * 4);
    short*        t2          = (short*)take((size_t)N * 64);       // 64B rows w/ scale
    float*        h2          = (float*)take((size_t)N * 16 * 4);
    short*        t3          = (short*)take((size_t)N * 8);        // 8B rows w/ scale
    float*        h3          = (float*)take((size_t)N * 2 * 4);
    const size_t needed = off;

    const int B = 256;
    const int nodeBlocks = (N + B - 1) / B;
    const dim3 linGrid(nodeBlocks, 2);       // y=0: rel(quant)->t, y=1: root+b->acc
    const bool packOK = (N <= (1 << 17)) && (NB <= NB_MAX) && (C <= CMAX);

    if (ws_size >= needed && packOK) {
        // ---- build: zero-global-atomic deterministic CSR ----
        hist_chunked_kernel<<<C, 512, 0, stream>>>(dst, chunkhist, nE, NB);
        scan_chunkhist_kernel<<<NB, CMAX, 0, stream>>>(chunkhist, gtotal, C, NB);
        scan_buckets_kernel<<<1, NB_MAX, 0, stream>>>(gtotal, bptr, NB, nE);
        bucketize_det_kernel<<<C, 512, 0, stream>>>(src, dst, chunkhist, bptr, records, nE, NB);
        place_merge_kernel<<<NB, 512, 0, stream>>>(records, bptr, rowptr, srcs_sorted, N, nE, NB);

        // ---- Layer 1: 64 -> 32 (CONTROL gather: 2 reqs/edge) ----
        linear_q2_kernel<64, 32, false><<<linGrid, B, 0, stream>>>(
            z, Wrel1, Wroot1, b1, t1, s1, h1, N);
        gather_agg_q_kernel<32, false><<<((size_t)N * 16 + B - 1) / B, B, 0, stream>>>(
            t1, s1, rowptr, srcs_sorted, h1, h1, N);

        // ---- Layer 2: 32 -> 16 (scale-in-line: 1 req/edge) ----
        linear_q2_kernel<32, 16, true><<<linGrid, B, 0, stream>>>(
            h1, Wrel2, Wroot2, b2, t2, nullptr, h2, N);
        gather16_inl_kernel<<<((size_t)N * 8 + B - 1) / B, B, 0, stream>>>(
            t2, rowptr, srcs_sorted, h2, h2, N);

        // ---- Layer 3: 16 -> 2 (8B rows, 4 lanes/node, softmax fused) ----
        linear_q2_kernel<16, 2, true><<<linGrid, B, 0, stream>>>(
            h2, Wrel3, Wroot3, b3, t3, nullptr, h3, N);
        gather2_inl_kernel<<<((size_t)N * 4 + B - 1) / B, B, 0, stream>>>(
            t3, rowptr, srcs_sorted, h3, (float*)d_out, N);
    } else {
        // ---- fallback: R2 atomic-scatter path (all f32, ping-pong layout) ----
        float* regionA = (float*)d_ws;
        float* regionB = regionA + (size_t)N * 32;
        float* ft1 = regionA;
        float* fh1 = regionB;
        float* ft2 = regionA;
        float* fh2 = regionA + (size_t)N * 16;
        float* ft3 = regionB;
        float* fh3 = regionB + (size_t)N * 2;
        linear2_kernel<64, 32, false><<<linGrid, B, 0, stream>>>(z, Wrel1, Wroot1, b1, ft1, fh1, N);
        scatter_kernel<32><<<((size_t)nE * 32 + B - 1) / B, B, 0, stream>>>(ft1, src, dst, fh1, nE);
        linear2_kernel<32, 16, true><<<linGrid, B, 0, stream>>>(fh1, Wrel2, Wroot2, b2, ft2, fh2, N);
        scatter_kernel<16><<<((size_t)nE * 16 + B - 1) / B, B, 0, stream>>>(ft2, src, dst, fh2, nE);
        linear2_kernel<16, 2, true><<<linGrid, B, 0, stream>>>(fh2, Wrel3, Wroot3, b3, ft3, fh3, N);
        scatter_kernel<2><<<((size_t)nE * 2 + B - 1) / B, B, 0, stream>>>(ft3, src, dst, fh3, nE);
        softmax2_kernel<<<nodeBlocks, B, 0, stream>>>(fh3, (float*)d_out, N);
    }
}